// Round 9
// baseline (413.320 us; speedup 1.0000x reference)
//
#include <hip/hip_runtime.h>

#define N_NODES 100000
#define N_EDGES 1000000
#define DIM 64
#define BN_EPS 1e-5f

#define CAP 40               // per-node bucket capacity (deg~Poisson(10))
#define NSEG 100             // coarse segments of 1000 nodes
#define SEG_NODES 1000
#define SEGCAP 11200         // pairs per segment buffer (avg 10000, +12 sigma)
#define BCAP 48              // LDS bucket cap in phase 1 (lambda ~30.7)
#define EPB 3072             // edges per phase-1 chunk
#define NBIN1 326            // ceil(1e6 / 3072)
#define CONV_CHUNKS 3125     // 800000 threads x 8 floats: bf16 conversion
#define TOTAL_P1 (NBIN1 + CONV_CHUNKS + 1)
#define OVF_CAP 4096
#define SPLITB 4
#define SEG_Q (SEG_NODES / SPLITB)   // 250
#define NTILES (N_NODES / 32)        // 3125
#define MAXT 5               // register-carried C-fragments per block

typedef __attribute__((ext_vector_type(8))) short short8_t;   // 8 bf16
typedef __attribute__((ext_vector_type(4))) float f32x4;      // MFMA C/D

// ---------------------------------------------------------------------------
// bf16 helpers (RNE pack, shift unpack)
// ---------------------------------------------------------------------------
__device__ inline unsigned bf16rne(float f) {
    unsigned u = __float_as_uint(f);
    return (u + 0x7FFFu + ((u >> 16) & 1u)) >> 16;
}
__device__ inline unsigned pack2(float a, float b) {
    return bf16rne(a) | (bf16rne(b) << 16);
}
__device__ inline void unp_add(unsigned d, float& e0, float& e1) {
    e0 += __uint_as_float(d << 16);
    e1 += __uint_as_float(d & 0xFFFF0000u);
}
__device__ inline void add8(float* acc, uint4 v) {
    unp_add(v.x, acc[0], acc[1]);
    unp_add(v.y, acc[2], acc[3]);
    unp_add(v.z, acc[4], acc[5]);
    unp_add(v.w, acc[6], acc[7]);
}

// Device-scope grid barrier (counter pre-zeroed by host memset; one slot per
// use). All blocks co-resident by construction (grid <= occupancy capacity).
__device__ inline void gbar(int* bar, int nblk) {
    __syncthreads();
    if (threadIdx.x == 0) {
        __hip_atomic_fetch_add(bar, 1, __ATOMIC_ACQ_REL, __HIP_MEMORY_SCOPE_AGENT);
        while (__hip_atomic_load(bar, __ATOMIC_ACQUIRE, __HIP_MEMORY_SCOPE_AGENT) < nblk)
            __builtin_amdgcn_s_sleep(2);
    }
    __syncthreads();
}

union SharedU {
    struct { int cnt[NSEG]; int base[NSEG]; uint2 pairs[NSEG][BCAP]; } p1; // 39.2 KB
    struct { int lcnt[SEG_Q]; } p2;
    struct { unsigned short ab[32 * 72]; float red0[4][32]; float red1[4][32]; } p3;
    struct { float ss[2][DIM]; } p4;
};

// ---------------------------------------------------------------------------
// The whole pipeline as one persistent kernel with 3 grid barriers.
// ---------------------------------------------------------------------------
__global__ __launch_bounds__(256) void k_mega(
        const int* __restrict__ ei, const float4* __restrict__ x4,
        const float* __restrict__ W, const float* __restrict__ bias,
        const float* __restrict__ gamma, const float* __restrict__ beta,
        float* __restrict__ out,
        int* __restrict__ seg_cnt, int* __restrict__ ovf_cnt,
        int* __restrict__ bar, uint2* __restrict__ ovf,
        uint4* __restrict__ xh, unsigned short* __restrict__ Wb,
        int* __restrict__ count, int* __restrict__ srcs,
        uint2* __restrict__ seg_buf, float* __restrict__ stats8,
        int nblk) {
    __shared__ SharedU sh;
    const int lane = threadIdx.x & 63;
    const int wave = threadIdx.x >> 6;

    // ================= Phase 1: bin edges + bf16 conversions =================
    for (int vb = blockIdx.x; vb < TOTAL_P1; vb += gridDim.x) {
        if (vb == NBIN1 + CONV_CHUNKS) {          // W fp32 -> bf16
            for (int t = threadIdx.x; t < DIM * DIM / 2; t += 256) {
                float2 w2 = ((const float2*)W)[t];
                ((unsigned*)Wb)[t] = pack2(w2.x, w2.y);
            }
            continue;
        }
        if (vb >= NBIN1) {                        // x fp32 -> bf16 (row g+1)
            int g = (vb - NBIN1) * 256 + threadIdx.x;
            float4 lo = x4[2 * g];
            float4 hi = x4[2 * g + 1];
            uint4 r;
            r.x = pack2(lo.x, lo.y);
            r.y = pack2(lo.z, lo.w);
            r.z = pack2(hi.x, hi.y);
            r.w = pack2(hi.z, hi.w);
            xh[8 + g] = r;
            continue;
        }
        // edge chunk
        __syncthreads();
        for (int t = threadIdx.x; t < NSEG; t += 256) sh.p1.cnt[t] = 0;
        __syncthreads();
        const int base4 = vb * (EPB / 4);
#pragma unroll
        for (int kk = 0; kk < 3; ++kk) {
            int i4 = base4 + kk * 256 + threadIdx.x;
            if (i4 < N_EDGES / 4) {
                int4 s4 = ((const int4*)ei)[i4];
                int4 d4 = ((const int4*)(ei + N_EDGES))[i4];
                int ssx[4] = {s4.x, s4.y, s4.z, s4.w};
                int ddx[4] = {d4.x, d4.y, d4.z, d4.w};
#pragma unroll
                for (int q = 0; q < 4; ++q) {
                    int seg = (unsigned)ddx[q] / SEG_NODES;
                    int p = atomicAdd(&sh.p1.cnt[seg], 1);      // LDS atomic
                    if (p < BCAP) {
                        sh.p1.pairs[seg][p] = make_uint2((unsigned)ssx[q], (unsigned)ddx[q]);
                    } else {                                     // rare spill
                        int g = atomicAdd(ovf_cnt, 1);
                        if (g < OVF_CAP) ovf[g] = make_uint2((unsigned)ssx[q], (unsigned)ddx[q]);
                    }
                }
            }
        }
        __syncthreads();
        if (threadIdx.x < NSEG) {
            int c = min(sh.p1.cnt[threadIdx.x], BCAP);
            sh.p1.base[threadIdx.x] = atomicAdd(&seg_cnt[threadIdx.x], c);
        }
        __syncthreads();
        for (int seg = wave; seg < NSEG; seg += 4) {
            int c = min(sh.p1.cnt[seg], BCAP);
            int bs = sh.p1.base[seg];
            for (int i = lane; i < c; i += 64) {
                int pos = bs + i;
                if (pos < SEGCAP) seg_buf[seg * SEGCAP + pos] = sh.p1.pairs[seg][i];
            }
        }
    }
    gbar(&bar[0], nblk);

    // ============ Phase 2: per-(segment, quarter) exact slot assignment ======
    for (int vb = blockIdx.x; vb < NSEG * SPLITB; vb += gridDim.x) {
        const int s = vb >> 2, q = vb & 3;
        __syncthreads();
        for (int t = threadIdx.x; t < SEG_Q; t += 256) sh.p2.lcnt[t] = 0;
        __syncthreads();
        int n = seg_cnt[s];
        if (n > SEGCAP) n = SEGCAP;
        const uint2* sb = seg_buf + s * SEGCAP;
        const int lo = q * SEG_Q, hi = lo + SEG_Q;
        for (int i = threadIdx.x; i < n; i += 256) {
            uint2 pr = sb[i];
            int dl = (int)pr.y - s * SEG_NODES;
            if (dl >= lo && dl < hi) {
                int p = atomicAdd(&sh.p2.lcnt[dl - lo], 1);     // LDS atomic
                if (p < CAP) srcs[(int)pr.y * CAP + p] = (int)pr.x;
            }
        }
        int oc = *ovf_cnt;
        if (oc > OVF_CAP) oc = OVF_CAP;
        for (int t = threadIdx.x; t < oc; t += 256) {
            uint2 pr = ovf[t];
            int dl = (int)pr.y - s * SEG_NODES;
            if (dl >= lo && dl < hi) {
                int p = atomicAdd(&sh.p2.lcnt[dl - lo], 1);
                if (p < CAP) srcs[(int)pr.y * CAP + p] = (int)pr.x;
            }
        }
        __syncthreads();
        for (int t = threadIdx.x; t < SEG_Q; t += 256)
            count[s * SEG_NODES + lo + t] = sh.p2.lcnt[t];
    }
    gbar(&bar[1], nblk);

    // ============ Phase 3: gather + mean + MFMA linear + BN stats ===========
    const int sub = lane >> 3, f8 = lane & 7;
    const int mh = wave & 1, nh = wave >> 1;
    const int m = lane & 15, quad = lane >> 4;

    const unsigned short* bp0 = Wb + (nh * 32 + m) * 64 + quad * 8;
    short8_t b00 = *(const short8_t*)bp0;
    short8_t b01 = *(const short8_t*)(bp0 + 32);
    const unsigned short* bp1 = bp0 + 16 * 64;
    short8_t b10 = *(const short8_t*)bp1;
    short8_t b11 = *(const short8_t*)(bp1 + 32);
    const float bj0 = bias[nh * 32 + m];
    const float bj1 = bias[nh * 32 + 16 + m];

    f32x4 cst[MAXT][2];
    int k = 0;
    for (int tile = blockIdx.x; tile < NTILES; tile += gridDim.x, ++k) {
        const int row = tile * 32 + wave * 8 + sub;
        float acc[8] = {0.f, 0.f, 0.f, 0.f, 0.f, 0.f, 0.f, 0.f};
        add8(acc, xh[(row + 1) * 8 + f8]);        // self loop
        const int ctrue = count[row];
        const int c = (ctrue < CAP) ? ctrue : CAP;
        const int* sp = srcs + row * CAP;
        for (int i = 0; i < c; i += 4) {
            int4 e = *(const int4*)(sp + i);
            int e1 = (i + 1 < c) ? e.y : -1;
            int e2 = (i + 2 < c) ? e.z : -1;
            int e3 = (i + 3 < c) ? e.w : -1;
            uint4 v0 = xh[(e.x + 1) * 8 + f8];
            uint4 v1 = xh[(e1 + 1) * 8 + f8];
            uint4 v2 = xh[(e2 + 1) * 8 + f8];
            uint4 v3 = xh[(e3 + 1) * 8 + f8];
            add8(acc, v0);
            add8(acc, v1);
            add8(acc, v2);
            add8(acc, v3);
        }
        const float inv = 1.0f / (float)(ctrue + 1);
#pragma unroll
        for (int j = 0; j < 8; ++j) acc[j] *= inv;

        __syncthreads();                          // protect ab/red reuse
        uint4 pk;
        pk.x = pack2(acc[0], acc[1]);
        pk.y = pack2(acc[2], acc[3]);
        pk.z = pack2(acc[4], acc[5]);
        pk.w = pack2(acc[6], acc[7]);
        *(uint4*)&sh.p3.ab[(wave * 8 + sub) * 72 + f8 * 8] = pk;
        __syncthreads();

        const unsigned short* ap = &sh.p3.ab[(mh * 16 + m) * 72 + quad * 8];
        short8_t a0 = *(const short8_t*)ap;
        short8_t a1 = *(const short8_t*)(ap + 32);

        f32x4 c0 = {0.f, 0.f, 0.f, 0.f}, c1 = {0.f, 0.f, 0.f, 0.f};
        c0 = __builtin_amdgcn_mfma_f32_16x16x32_bf16(a0, b00, c0, 0, 0, 0);
        c0 = __builtin_amdgcn_mfma_f32_16x16x32_bf16(a1, b01, c0, 0, 0, 0);
        c1 = __builtin_amdgcn_mfma_f32_16x16x32_bf16(a0, b10, c1, 0, 0, 0);
        c1 = __builtin_amdgcn_mfma_f32_16x16x32_bf16(a1, b11, c1, 0, 0, 0);

        const int rb = tile * 32 + mh * 16 + quad * 4;
#pragma unroll
        for (int f = 0; f < 2; ++f) {
            f32x4 cc = f ? c1 : c0;
            float bj = f ? bj1 : bj0;
            float q0 = 0.f, q1 = 0.f;
#pragma unroll
            for (int r = 0; r < 4; ++r) {
                float v = cc[r] + bj;
                cc[r] = v;
                q0 += v;
                q1 += v * v;
            }
            if (k < MAXT) cst[k][f] = cc;
            else {                                 // spill (small-grid safety)
                int col = nh * 32 + f * 16 + m;
#pragma unroll
                for (int r = 0; r < 4; ++r) out[(rb + r) * DIM + col] = cc[r];
            }
            q0 += __shfl_xor(q0, 16); q0 += __shfl_xor(q0, 32);
            q1 += __shfl_xor(q1, 16); q1 += __shfl_xor(q1, 32);
            if (quad == 0) {
                sh.p3.red0[wave][f * 16 + m] = q0;
                sh.p3.red1[wave][f * 16 + m] = q1;
            }
        }
        __syncthreads();
        if (threadIdx.x < DIM) {
            int j = threadIdx.x, jh = j >> 5, jl = j & 31;
            float t0 = sh.p3.red0[2 * jh][jl] + sh.p3.red0[2 * jh + 1][jl];
            float t1 = sh.p3.red1[2 * jh][jl] + sh.p3.red1[2 * jh + 1][jl];
            float* sb = stats8 + (blockIdx.x & 7) * 128;
            atomicAdd(&sb[j], t0);
            atomicAdd(&sb[DIM + j], t1);
        }
    }
    gbar(&bar[2], nblk);

    // ============ Phase 4: BN params + normalize + residual + relu ==========
    if (threadIdx.x < DIM) {
        int j = threadIdx.x;
        float s0 = 0.f, s1 = 0.f;
#pragma unroll
        for (int b = 0; b < 8; ++b) {
            s0 += stats8[b * 128 + j];
            s1 += stats8[b * 128 + DIM + j];
        }
        const float invN = 1.0f / (float)N_NODES;
        float mean = s0 * invN;
        float var = s1 * invN - mean * mean;
        float scale = gamma[j] * rsqrtf(var + BN_EPS);
        sh.p4.ss[0][j] = scale;
        sh.p4.ss[1][j] = beta[j] - mean * scale;
    }
    __syncthreads();

    const unsigned short* xh16 = (const unsigned short*)xh;
    k = 0;
    for (int tile = blockIdx.x; tile < NTILES; tile += gridDim.x, ++k) {
        const int rb = tile * 32 + mh * 16 + quad * 4;
#pragma unroll
        for (int f = 0; f < 2; ++f) {
            int col = nh * 32 + f * 16 + m;
            float sc = sh.p4.ss[0][col];
            float sf = sh.p4.ss[1][col];
#pragma unroll
            for (int r = 0; r < 4; ++r) {
                float v = (k < MAXT) ? cst[k][f][r] : out[(rb + r) * DIM + col];
                unsigned short h = xh16[(rb + r + 1) * 64 + col];
                float xr = __uint_as_float((unsigned)h << 16);
                out[(rb + r) * DIM + col] = fmaxf(fmaf(v, sc, sf) + xr, 0.f);
            }
        }
    }
}

// ---------------------------------------------------------------------------
extern "C" void kernel_launch(void* const* d_in, const int* in_sizes, int n_in,
                              void* d_out, int out_size, void* d_ws, size_t ws_size,
                              hipStream_t stream) {
    const float* x     = (const float*)d_in[0];
    const int*   ei    = (const int*)d_in[1];
    const float* W     = (const float*)d_in[2];
    const float* bias  = (const float*)d_in[3];
    const float* gamma = (const float*)d_in[4];
    const float* beta  = (const float*)d_in[5];
    float* out = (float*)d_out;

    // ws layout (bytes):
    //   stats8  @ 0          4096
    //   seg_cnt @ 4096       512
    //   ovf_cnt @ 4608       4
    //   bar     @ 4612       12
    //   ovf     @ 4736       32768          -> ends 37504
    //   xh      @ 37504      12800128       ((N+1) x 128 B; row 0 zeroed by
    //                                        the same memset: [0, 37632))
    //   Wb      @ 12837632   8192
    //   count   @ 12845824   400000
    //   srcs    @ 13245824   16000000       (N * CAP * 4)
    //   seg_buf @ 29245824   8960000        (NSEG * SEGCAP * 8)  -> 38205824
    char* ws = (char*)d_ws;
    float*          stats8  = (float*)(ws);
    int*            seg_cnt = (int*)(ws + 4096);
    int*            ovf_cnt = (int*)(ws + 4608);
    int*            bar     = (int*)(ws + 4612);
    uint2*          ovf     = (uint2*)(ws + 4736);
    uint4*          xh      = (uint4*)(ws + 37504);
    unsigned short* Wb      = (unsigned short*)(ws + 12837632);
    int*            count   = (int*)(ws + 12845824);
    int*            srcs    = (int*)(ws + 13245824);
    uint2*          seg_buf = (uint2*)(ws + 29245824);

    // Grid sized so all blocks are co-resident (required by the barriers).
    int ncu = 256;
    hipDeviceGetAttribute(&ncu, hipDeviceAttributeMultiprocessorCount, 0);
    int nb = 0;
    if (hipOccupancyMaxActiveBlocksPerMultiprocessor(&nb, k_mega, 256, 0)
            != hipSuccess || nb < 1)
        nb = 2;
    long nblk = (long)nb * ncu;
    if (nblk > 2048) nblk = 2048;
    if (nblk < 64) nblk = 64;

    hipMemsetAsync(ws, 0, 37632, stream);   // control block + xh zero row

    k_mega<<<(int)nblk, 256, 0, stream>>>(
        ei, (const float4*)x, W, bias, gamma, beta, out,
        seg_cnt, ovf_cnt, bar, ovf, xh, Wb, count, srcs, seg_buf, stats8,
        (int)nblk);
}

// Round 10
// 157.711 us; speedup vs baseline: 2.6207x; 2.6207x over previous
//
#include <hip/hip_runtime.h>

#define N_NODES 100000
#define N_EDGES 1000000
#define DIM 64
#define BN_EPS 1e-5f

#define CAP 40               // per-node bucket capacity (deg~Poisson(10))
#define NSEG 100             // coarse segments of 1000 nodes
#define SEG_NODES 1000
#define SEGCAP 11200         // pairs per segment buffer (avg 10000, wide margin)
#define BCAP 40              // LDS bucket cap in bin1 (lambda ~20.5)
#define EPB 2048             // edges per bin1 block
#define NBIN1 489            // ceil(1e6 / 2048)
#define CONV_BLOCKS 3125     // 800000 threads x 8 floats: bf16 conversion
#define OVF_CAP 4096
#define GATHER_BLOCKS (N_NODES / 32)

typedef __attribute__((ext_vector_type(8))) short short8_t;   // 8 bf16
typedef __attribute__((ext_vector_type(4))) float f32x4;      // MFMA C/D

// ---------------------------------------------------------------------------
// bf16 helpers (RNE pack, shift unpack)
// ---------------------------------------------------------------------------
__device__ inline unsigned bf16rne(float f) {
    unsigned u = __float_as_uint(f);
    return (u + 0x7FFFu + ((u >> 16) & 1u)) >> 16;
}
__device__ inline unsigned pack2(float a, float b) {
    return bf16rne(a) | (bf16rne(b) << 16);
}
__device__ inline void unp_add(unsigned d, float& e0, float& e1) {
    e0 += __uint_as_float(d << 16);
    e1 += __uint_as_float(d & 0xFFFF0000u);
}
__device__ inline void add8(float* acc, uint4 v) {
    unp_add(v.x, acc[0], acc[1]);
    unp_add(v.y, acc[2], acc[3]);
    unp_add(v.z, acc[4], acc[5]);
    unp_add(v.w, acc[6], acc[7]);
}

// ---------------------------------------------------------------------------
// Kernel 1a: coarse-bin edges by dst segment via LDS atomics; flush each
// bucket with ONE returning global atomic + coalesced pair writes.
// Extra blocks: bf16 conversion of x (rows shifted by 1; row 0 = zeros)
// and, in the last block, bf16 conversion of W.
// ---------------------------------------------------------------------------
__global__ __launch_bounds__(256) void k_bin1(const int* __restrict__ ei,
                                              const float4* __restrict__ x4,
                                              const float* __restrict__ W,
                                              uint2* __restrict__ seg_buf,
                                              int* __restrict__ seg_cnt,
                                              int* __restrict__ ovf_cnt,
                                              uint2* __restrict__ ovf,
                                              uint4* __restrict__ xh,
                                              unsigned short* __restrict__ Wb) {
    __shared__ int cnt[NSEG];
    __shared__ int base[NSEG];
    __shared__ uint2 pairs[NSEG][BCAP];

    int b = blockIdx.x;
    if (b == NBIN1 + CONV_BLOCKS) {       // W fp32 -> bf16 (4096 elems)
        for (int t = threadIdx.x; t < DIM * DIM / 2; t += 256) {
            float2 w2 = ((const float2*)W)[t];
            ((unsigned*)Wb)[t] = pack2(w2.x, w2.y);
        }
        return;
    }
    if (b >= NBIN1) {                     // bf16 conversion blocks for x
        int g = (b - NBIN1) * 256 + threadIdx.x;   // 0..799999 exactly
        float4 lo = x4[2 * g];
        float4 hi = x4[2 * g + 1];
        uint4 r;
        r.x = pack2(lo.x, lo.y);
        r.y = pack2(lo.z, lo.w);
        r.z = pack2(hi.x, hi.y);
        r.w = pack2(hi.z, hi.w);
        xh[8 + g] = r;
        return;
    }

    for (int t = threadIdx.x; t < NSEG; t += 256) cnt[t] = 0;
    __syncthreads();

    const int base4 = b * (EPB / 4);
#pragma unroll
    for (int k = 0; k < 2; ++k) {
        int i4 = base4 + k * 256 + threadIdx.x;
        if (i4 < N_EDGES / 4) {
            int4 s4 = ((const int4*)ei)[i4];
            int4 d4 = ((const int4*)(ei + N_EDGES))[i4];
            int ss[4] = {s4.x, s4.y, s4.z, s4.w};
            int dd[4] = {d4.x, d4.y, d4.z, d4.w};
#pragma unroll
            for (int q = 0; q < 4; ++q) {
                int seg = (unsigned)dd[q] / SEG_NODES;
                int p = atomicAdd(&cnt[seg], 1);           // LDS atomic
                if (p < BCAP) {
                    pairs[seg][p] = make_uint2((unsigned)ss[q], (unsigned)dd[q]);
                } else {                                    // rare spill
                    int g = atomicAdd(ovf_cnt, 1);
                    if (g < OVF_CAP) ovf[g] = make_uint2((unsigned)ss[q], (unsigned)dd[q]);
                }
            }
        }
    }
    __syncthreads();

    if (threadIdx.x < NSEG) {
        int c = min(cnt[threadIdx.x], BCAP);
        base[threadIdx.x] = atomicAdd(&seg_cnt[threadIdx.x], c);  // 100/block
    }
    __syncthreads();

    const int wave = threadIdx.x >> 6, lane = threadIdx.x & 63;
    for (int seg = wave; seg < NSEG; seg += 4) {
        int c = min(cnt[seg], BCAP);
        int bs = base[seg];
        for (int i = lane; i < c; i += 64) {
            int pos = bs + i;
            if (pos < SEGCAP) seg_buf[seg * SEGCAP + pos] = pairs[seg][i];
        }
    }
}

// ---------------------------------------------------------------------------
// Kernel 1b: one 1024-thread block per segment: exact per-dst slots via LDS
// atomics, scatter srcs into the segment's 160 KB slice, write count[].
// ---------------------------------------------------------------------------
__global__ __launch_bounds__(1024) void k_bin2(const uint2* __restrict__ seg_buf,
                                               const int* __restrict__ seg_cnt,
                                               const int* __restrict__ ovf_cnt,
                                               const uint2* __restrict__ ovf,
                                               int* __restrict__ srcs,
                                               int* __restrict__ count) {
    const int s = blockIdx.x;
    __shared__ int lcnt[SEG_NODES];
    for (int t = threadIdx.x; t < SEG_NODES; t += 1024) lcnt[t] = 0;
    __syncthreads();

    int n = seg_cnt[s];
    if (n > SEGCAP) n = SEGCAP;
    const uint2* sb = seg_buf + s * SEGCAP;

    auto place = [&](uint2 pr) {
        int dl = (int)pr.y - s * SEG_NODES;
        int p = atomicAdd(&lcnt[dl], 1);                  // LDS atomic
        if (p < CAP) srcs[(int)pr.y * CAP + p] = (int)pr.x;
    };

    int i = threadIdx.x;
    for (; i + 1024 < n; i += 2048) {                      // 2-way ILP
        uint2 a0 = sb[i];
        uint2 a1 = sb[i + 1024];
        place(a0); place(a1);
    }
    for (; i < n; i += 1024) place(sb[i]);

    int oc = *ovf_cnt;                                    // usually 0
    if (oc > OVF_CAP) oc = OVF_CAP;
    for (int t = threadIdx.x; t < oc; t += 1024) {
        uint2 pr = ovf[t];
        if ((int)((unsigned)pr.y / SEG_NODES) == s) place(pr);
    }
    __syncthreads();

    for (int t = threadIdx.x; t < SEG_NODES; t += 1024)
        count[s * SEG_NODES + t] = lcnt[t];
}

// ---------------------------------------------------------------------------
// Legacy fallback fill: returning global atomics; used only if ws too small.
// ---------------------------------------------------------------------------
__global__ __launch_bounds__(256) void k_fill_legacy(const int* __restrict__ ei,
                                                     const float4* __restrict__ x4,
                                                     const float* __restrict__ W,
                                                     int* __restrict__ count,
                                                     int* __restrict__ srcs,
                                                     uint4* __restrict__ xh,
                                                     unsigned short* __restrict__ Wb) {
    int b = blockIdx.x;
    if (b == 977 + CONV_BLOCKS) {
        for (int t = threadIdx.x; t < DIM * DIM / 2; t += 256) {
            float2 w2 = ((const float2*)W)[t];
            ((unsigned*)Wb)[t] = pack2(w2.x, w2.y);
        }
        return;
    }
    if (b < 977) {
        int t = b * 256 + threadIdx.x;
        if (t < N_EDGES / 4) {
            int4 s4 = ((const int4*)ei)[t];
            int4 d4 = ((const int4*)(ei + N_EDGES))[t];
            int p0 = atomicAdd(&count[d4.x], 1);
            int p1 = atomicAdd(&count[d4.y], 1);
            int p2 = atomicAdd(&count[d4.z], 1);
            int p3 = atomicAdd(&count[d4.w], 1);
            if (p0 < CAP) srcs[d4.x * CAP + p0] = s4.x;
            if (p1 < CAP) srcs[d4.y * CAP + p1] = s4.y;
            if (p2 < CAP) srcs[d4.z * CAP + p2] = s4.z;
            if (p3 < CAP) srcs[d4.w * CAP + p3] = s4.w;
        }
    } else {
        int g = (b - 977) * 256 + threadIdx.x;
        float4 lo = x4[2 * g];
        float4 hi = x4[2 * g + 1];
        uint4 r;
        r.x = pack2(lo.x, lo.y);
        r.y = pack2(lo.z, lo.w);
        r.z = pack2(hi.x, hi.y);
        r.w = pack2(hi.z, hi.w);
        xh[8 + g] = r;
    }
}

// ---------------------------------------------------------------------------
// Kernel 2: fused gather(bf16) + mean + MFMA linear + BN stats. (R8 version)
// ---------------------------------------------------------------------------
__global__ __launch_bounds__(256) void k_gather_linear(
        const uint4* __restrict__ xh,     // [(N+1)][8] uint4, row 0 = zeros
        const int* __restrict__ count,
        const int* __restrict__ srcs,
        const unsigned short* __restrict__ Wb,   // [64][64] bf16
        const float* __restrict__ bias,
        float* __restrict__ lin_out,
        float* __restrict__ stats8) {
    const int lane = threadIdx.x & 63;
    const int wave = threadIdx.x >> 6;
    const int sub  = lane >> 3;
    const int f8   = lane & 7;

    __shared__ unsigned short ab[32 * 72];    // 32 rows x 64 bf16, stride 72
    __shared__ float red0[4][32], red1[4][32];

    // ---- gather + mean ----
    const int row = blockIdx.x * 32 + wave * 8 + sub;
    float acc[8] = {0.f, 0.f, 0.f, 0.f, 0.f, 0.f, 0.f, 0.f};
    add8(acc, xh[(row + 1) * 8 + f8]);    // self loop

    const int ctrue = count[row];
    const int c = (ctrue < CAP) ? ctrue : CAP;
    const int* sp = srcs + row * CAP;
    for (int i = 0; i < c; i += 4) {
        int4 e = *(const int4*)(sp + i);
        int e1 = (i + 1 < c) ? e.y : -1;
        int e2 = (i + 2 < c) ? e.z : -1;
        int e3 = (i + 3 < c) ? e.w : -1;
        uint4 v0 = xh[(e.x + 1) * 8 + f8];
        uint4 v1 = xh[(e1 + 1) * 8 + f8];
        uint4 v2 = xh[(e2 + 1) * 8 + f8];
        uint4 v3 = xh[(e3 + 1) * 8 + f8];
        add8(acc, v0);
        add8(acc, v1);
        add8(acc, v2);
        add8(acc, v3);
    }

    const float inv = 1.0f / (float)(ctrue + 1);
#pragma unroll
    for (int k = 0; k < 8; ++k) acc[k] *= inv;

    // ---- stage aggr tile to LDS as bf16 ----
    uint4 pk;
    pk.x = pack2(acc[0], acc[1]);
    pk.y = pack2(acc[2], acc[3]);
    pk.z = pack2(acc[4], acc[5]);
    pk.w = pack2(acc[6], acc[7]);
    *(uint4*)&ab[(wave * 8 + sub) * 72 + f8 * 8] = pk;
    __syncthreads();

    // ---- MFMA: lin[32][64] = aggr[32][64] @ W^T ----
    const int mh = wave & 1, nh = wave >> 1;    // quadrant
    const int m = lane & 15, quad = lane >> 4;

    const unsigned short* ap = &ab[(mh * 16 + m) * 72 + quad * 8];
    short8_t a0 = *(const short8_t*)ap;          // k = 0..31
    short8_t a1 = *(const short8_t*)(ap + 32);   // k = 32..63

    const unsigned short* bp0 = Wb + (nh * 32 + m) * 64 + quad * 8;
    short8_t b00 = *(const short8_t*)bp0;
    short8_t b01 = *(const short8_t*)(bp0 + 32);
    const unsigned short* bp1 = bp0 + 16 * 64;
    short8_t b10 = *(const short8_t*)bp1;
    short8_t b11 = *(const short8_t*)(bp1 + 32);

    f32x4 c0 = {0.f, 0.f, 0.f, 0.f}, c1 = {0.f, 0.f, 0.f, 0.f};
    c0 = __builtin_amdgcn_mfma_f32_16x16x32_bf16(a0, b00, c0, 0, 0, 0);
    c0 = __builtin_amdgcn_mfma_f32_16x16x32_bf16(a1, b01, c0, 0, 0, 0);
    c1 = __builtin_amdgcn_mfma_f32_16x16x32_bf16(a0, b10, c1, 0, 0, 0);
    c1 = __builtin_amdgcn_mfma_f32_16x16x32_bf16(a1, b11, c1, 0, 0, 0);

    // ---- epilogue: bias, store, per-feature stats ----
    const int rb = blockIdx.x * 32 + mh * 16 + quad * 4;
#pragma unroll
    for (int f = 0; f < 2; ++f) {
        f32x4 cc = f ? c1 : c0;
        int col = nh * 32 + f * 16 + m;          // C/D: col=lane&15
        float bj = bias[col];
        float q0 = 0.f, q1 = 0.f;
#pragma unroll
        for (int r = 0; r < 4; ++r) {            // C/D: row=quad*4+r
            float v = cc[r] + bj;
            lin_out[(rb + r) * DIM + col] = v;
            q0 += v;
            q1 += v * v;
        }
        q0 += __shfl_xor(q0, 16); q0 += __shfl_xor(q0, 32);
        q1 += __shfl_xor(q1, 16); q1 += __shfl_xor(q1, 32);
        if (quad == 0) {
            red0[wave][f * 16 + m] = q0;
            red1[wave][f * 16 + m] = q1;
        }
    }
    __syncthreads();
    if (threadIdx.x < DIM) {
        int j = threadIdx.x, jh = j >> 5, jl = j & 31;
        float t0 = red0[2 * jh][jl] + red0[2 * jh + 1][jl];
        float t1 = red1[2 * jh][jl] + red1[2 * jh + 1][jl];
        float* sb = stats8 + (blockIdx.x & 7) * 128;
        atomicAdd(&sb[j], t0);
        atomicAdd(&sb[DIM + j], t1);
    }
}

// ---------------------------------------------------------------------------
// Kernel 3: out = relu(lin*scale + shift + x_bf16), BN params from stats.
// Residual read from the bf16 copy (xh) to cut 12.8 MB of HBM traffic.
// ---------------------------------------------------------------------------
__global__ __launch_bounds__(256) void k_final(const float4* lin4,
                                               const unsigned short* __restrict__ xh16,
                                               const float* __restrict__ stats8,
                                               const float* __restrict__ gamma,
                                               const float* __restrict__ beta,
                                               float4* out4) {
    __shared__ float ss[2][DIM];
    if (threadIdx.x < DIM) {
        int j = threadIdx.x;
        float s0 = 0.f, s1 = 0.f;
#pragma unroll
        for (int b = 0; b < 8; ++b) {
            s0 += stats8[b * 128 + j];
            s1 += stats8[b * 128 + DIM + j];
        }
        const float invN = 1.0f / (float)N_NODES;
        float mean = s0 * invN;
        float var = s1 * invN - mean * mean;
        float scale = gamma[j] * rsqrtf(var + BN_EPS);
        ss[0][j] = scale;
        ss[1][j] = beta[j] - mean * scale;
    }
    __syncthreads();
    int tid = blockIdx.x * blockDim.x + threadIdx.x;
    int row = tid >> 4;
    int j4 = (tid & 15) * 4;
    float4 l = lin4[tid];
    ushort2 h01 = *(const ushort2*)&xh16[(row + 1) * 64 + j4];
    ushort2 h23 = *(const ushort2*)&xh16[(row + 1) * 64 + j4 + 2];
    float4 o;
    o.x = fmaxf(fmaf(l.x, ss[0][j4 + 0], ss[1][j4 + 0])
                + __uint_as_float((unsigned)h01.x << 16), 0.f);
    o.y = fmaxf(fmaf(l.y, ss[0][j4 + 1], ss[1][j4 + 1])
                + __uint_as_float((unsigned)h01.y << 16), 0.f);
    o.z = fmaxf(fmaf(l.z, ss[0][j4 + 2], ss[1][j4 + 2])
                + __uint_as_float((unsigned)h23.x << 16), 0.f);
    o.w = fmaxf(fmaf(l.w, ss[0][j4 + 3], ss[1][j4 + 3])
                + __uint_as_float((unsigned)h23.y << 16), 0.f);
    out4[tid] = o;
}

// ---------------------------------------------------------------------------
extern "C" void kernel_launch(void* const* d_in, const int* in_sizes, int n_in,
                              void* d_out, int out_size, void* d_ws, size_t ws_size,
                              hipStream_t stream) {
    const float* x     = (const float*)d_in[0];
    const int*   ei    = (const int*)d_in[1];
    const float* W     = (const float*)d_in[2];
    const float* bias  = (const float*)d_in[3];
    const float* gamma = (const float*)d_in[4];
    const float* beta  = (const float*)d_in[5];
    float* out = (float*)d_out;

    // ws layout (bytes):
    //   stats8  @ 0          4096
    //   seg_cnt @ 4096       512
    //   ovf_cnt @ 4608       128
    //   ovf     @ 4736       32768          -> ends 37504
    //   xh      @ 37504      12800128       ((N+1) x 128 B; row 0 zeroed by
    //                                        the same memset: [0, 37632))
    //   Wb      @ 12837632   8192
    //   count   @ 12845824   400000
    //   srcs    @ 13245824   16000000       (N * CAP * 4)
    //   seg_buf @ 29245824   8960000        (NSEG * SEGCAP * 8)  -> 38205824
    char* ws = (char*)d_ws;
    float*          stats8  = (float*)(ws);
    int*            seg_cnt = (int*)(ws + 4096);
    int*            ovf_cnt = (int*)(ws + 4608);
    uint2*          ovf     = (uint2*)(ws + 4736);
    uint4*          xh      = (uint4*)(ws + 37504);
    unsigned short* Wb      = (unsigned short*)(ws + 12837632);
    int*            count   = (int*)(ws + 12845824);
    int*            srcs    = (int*)(ws + 13245824);
    uint2*          seg_buf = (uint2*)(ws + 29245824);

    const size_t NEED_BIN = 38205824;

    if (ws_size >= NEED_BIN) {
        hipMemsetAsync(ws, 0, 37632, stream);   // stats8/seg_cnt/ovf + xh row0
        k_bin1<<<NBIN1 + CONV_BLOCKS + 1, 256, 0, stream>>>(
            ei, (const float4*)x, W, seg_buf, seg_cnt, ovf_cnt, ovf, xh, Wb);
        k_bin2<<<NSEG, 1024, 0, stream>>>(seg_buf, seg_cnt, ovf_cnt, ovf,
                                          srcs, count);
    } else {
        hipMemsetAsync(ws, 0, 37632, stream);
        hipMemsetAsync(count, 0, 400000, stream);
        k_fill_legacy<<<977 + CONV_BLOCKS + 1, 256, 0, stream>>>(
            ei, (const float4*)x, W, count, srcs, xh, Wb);
    }

    k_gather_linear<<<GATHER_BLOCKS, 256, 0, stream>>>(
        xh, count, srcs, Wb, bias, out, stats8);

    k_final<<<N_NODES * (DIM / 4) / 256, 256, 0, stream>>>(
        (const float4*)out, (const unsigned short*)xh, stats8, gamma, beta,
        (float4*)out);
}

// Round 11
// 146.277 us; speedup vs baseline: 2.8256x; 1.0782x over previous
//
#include <hip/hip_runtime.h>

#define N_NODES 100000
#define N_EDGES 1000000
#define DIM 64
#define BN_EPS 1e-5f

#define CAP 40               // per-node list capacity (deg~Poisson(10))
#define SEG_SHIFT 10
#define SEG_NODES 1024       // power of 2: 32-row tiles never straddle segs
#define NSEG 98              // ceil(100000/1024)
#define SEGCAP 11264         // pairs per segment (avg 10240, wide margin)
#define BCAP 96              // LDS bucket cap in bin1 (lambda ~41.8)
#define EPB 4096             // edges per bin1 block
#define NBIN1 245            // ceil(1e6/4096)
#define CONV_BLOCKS 3125     // 800000 threads x 8 floats: bf16 conversion
#define OVF_CAP 4096
#define GATHER_BLOCKS (N_NODES / 32)   // 3125

typedef __attribute__((ext_vector_type(8))) short short8_t;   // 8 bf16
typedef __attribute__((ext_vector_type(4))) float f32x4;      // MFMA C/D

// ---------------------------------------------------------------------------
// bf16 helpers (RNE pack, shift unpack)
// ---------------------------------------------------------------------------
__device__ inline unsigned bf16rne(float f) {
    unsigned u = __float_as_uint(f);
    return (u + 0x7FFFu + ((u >> 16) & 1u)) >> 16;
}
__device__ inline unsigned pack2(float a, float b) {
    return bf16rne(a) | (bf16rne(b) << 16);
}
__device__ inline void unp_add(unsigned d, float& e0, float& e1) {
    e0 += __uint_as_float(d << 16);
    e1 += __uint_as_float(d & 0xFFFF0000u);
}
__device__ inline void add8(float* acc, uint4 v) {
    unp_add(v.x, acc[0], acc[1]);
    unp_add(v.y, acc[2], acc[3]);
    unp_add(v.z, acc[4], acc[5]);
    unp_add(v.w, acc[6], acc[7]);
}

// ---------------------------------------------------------------------------
// Kernel 1: coarse-bin edges by dst segment via LDS atomics; pairs packed as
// (dst&1023)<<17 | src (27 bits). Flush per (block,segment) with one
// returning global atomic + coalesced uint writes.
// Extra blocks: bf16 conversion of x (rows shifted by 1; row 0 = zeros)
// and, in the last block, bf16 conversion of W.
// ---------------------------------------------------------------------------
__global__ __launch_bounds__(256) void k_bin1(const int* __restrict__ ei,
                                              const float4* __restrict__ x4,
                                              const float* __restrict__ W,
                                              unsigned* __restrict__ seg_buf,
                                              int* __restrict__ seg_cnt,
                                              int* __restrict__ ovf_cnt,
                                              uint2* __restrict__ ovf,
                                              uint4* __restrict__ xh,
                                              unsigned short* __restrict__ Wb) {
    __shared__ int cnt[NSEG];
    __shared__ int base[NSEG];
    __shared__ unsigned pairs[NSEG][BCAP];

    int b = blockIdx.x;
    if (b == NBIN1 + CONV_BLOCKS) {       // W fp32 -> bf16 (4096 elems)
        for (int t = threadIdx.x; t < DIM * DIM / 2; t += 256) {
            float2 w2 = ((const float2*)W)[t];
            ((unsigned*)Wb)[t] = pack2(w2.x, w2.y);
        }
        return;
    }
    if (b >= NBIN1) {                     // bf16 conversion blocks for x
        int g = (b - NBIN1) * 256 + threadIdx.x;   // 0..799999 exactly
        float4 lo = x4[2 * g];
        float4 hi = x4[2 * g + 1];
        uint4 r;
        r.x = pack2(lo.x, lo.y);
        r.y = pack2(lo.z, lo.w);
        r.z = pack2(hi.x, hi.y);
        r.w = pack2(hi.z, hi.w);
        xh[8 + g] = r;
        return;
    }

    for (int t = threadIdx.x; t < NSEG; t += 256) cnt[t] = 0;
    __syncthreads();

    const int base4 = b * (EPB / 4);
#pragma unroll
    for (int k = 0; k < 4; ++k) {
        int i4 = base4 + k * 256 + threadIdx.x;
        if (i4 < N_EDGES / 4) {
            int4 s4 = ((const int4*)ei)[i4];
            int4 d4 = ((const int4*)(ei + N_EDGES))[i4];
            int ss[4] = {s4.x, s4.y, s4.z, s4.w};
            int dd[4] = {d4.x, d4.y, d4.z, d4.w};
#pragma unroll
            for (int q = 0; q < 4; ++q) {
                int seg = (unsigned)dd[q] >> SEG_SHIFT;
                unsigned pk = ((unsigned)(dd[q] & (SEG_NODES - 1)) << 17)
                            | (unsigned)ss[q];
                int p = atomicAdd(&cnt[seg], 1);           // LDS atomic
                if (p < BCAP) {
                    pairs[seg][p] = pk;
                } else {                                    // rare spill
                    int g = atomicAdd(ovf_cnt, 1);
                    if (g < OVF_CAP) ovf[g] = make_uint2((unsigned)ss[q], (unsigned)dd[q]);
                }
            }
        }
    }
    __syncthreads();

    if (threadIdx.x < NSEG) {
        int c = min(cnt[threadIdx.x], BCAP);
        base[threadIdx.x] = atomicAdd(&seg_cnt[threadIdx.x], c);  // 98/block
    }
    __syncthreads();

    const int wave = threadIdx.x >> 6, lane = threadIdx.x & 63;
    for (int seg = wave; seg < NSEG; seg += 4) {
        int c = min(cnt[seg], BCAP);
        int bs = base[seg];
        for (int i = lane; i < c; i += 64) {
            int pos = bs + i;
            if (pos < SEGCAP) seg_buf[seg * SEGCAP + pos] = pairs[seg][i];
        }
    }
}

// ---------------------------------------------------------------------------
// Kernel 2: scan + gather(bf16) + mean + MFMA linear + BN stats.
// Block b owns 32 rows = window (b&31)*32 in segment b>>5. Phase A: scan the
// segment's packed pairs (L2-hot, 32x redundancy across sibling blocks),
// filter the window, build per-row src lists in LDS (LDS atomics; exact
// degree = lcnt). Phase B: 8 lanes x 16B per row -> 8 rows/wave, masked int4
// index batches from LDS. Phase C: MFMA 32x64x64 as in R8.
// ---------------------------------------------------------------------------
struct ScanS { int lcnt[32]; unsigned lists[32][CAP]; };
struct MmS { unsigned short ab[32 * 72]; float red0[4][32]; float red1[4][32]; };
union GatherU { ScanS sc; MmS mm; };

__global__ __launch_bounds__(256) void k_gather_linear(
        const uint4* __restrict__ xh,     // [(N+1)][8] uint4, row 0 = zeros
        const unsigned* __restrict__ seg_buf,
        const int* __restrict__ seg_cnt,
        const int* __restrict__ ovf_cnt,
        const uint2* __restrict__ ovf,
        const unsigned short* __restrict__ Wb,   // [64][64] bf16
        const float* __restrict__ bias,
        float* __restrict__ lin_out,
        float* __restrict__ stats8) {
    __shared__ GatherU sh;
    const int lane = threadIdx.x & 63;
    const int wave = threadIdx.x >> 6;
    const int seg = blockIdx.x >> 5;
    const int winbase = (blockIdx.x & 31) * 32;

    if (threadIdx.x < 32) sh.sc.lcnt[threadIdx.x] = 0;
    __syncthreads();

    // ---- Phase A: scan segment, build per-row lists ----
    int n = seg_cnt[seg];
    if (n > SEGCAP) n = SEGCAP;
    const unsigned* sb = seg_buf + seg * SEGCAP;

    auto proc = [&](unsigned p) {
        int wloc = (int)(p >> 17) - winbase;
        if ((unsigned)wloc < 32u) {
            int pos = atomicAdd(&sh.sc.lcnt[wloc], 1);    // LDS atomic
            if (pos < CAP) sh.sc.lists[wloc][pos] = p & 0x1FFFFu;
        }
    };

    for (int i = threadIdx.x * 4; i < n; i += 1024) {
        uint4 p4;
        if (i + 4 <= n) {
            p4 = *(const uint4*)(sb + i);
        } else {
            p4.x = sb[i];
            p4.y = (i + 1 < n) ? sb[i + 1] : 0xFFFFFFFFu;
            p4.z = (i + 2 < n) ? sb[i + 2] : 0xFFFFFFFFu;
            p4.w = 0xFFFFFFFFu;   // sentinel: wloc >> 32 -> filtered
        }
        proc(p4.x); proc(p4.y); proc(p4.z); proc(p4.w);
    }
    int oc = *ovf_cnt;                                    // usually 0
    if (oc > OVF_CAP) oc = OVF_CAP;
    for (int t = threadIdx.x; t < oc; t += 256) {
        uint2 pr = ovf[t];
        if ((int)(pr.y >> SEG_SHIFT) == seg) {
            int wloc = (int)(pr.y & (SEG_NODES - 1)) - winbase;
            if ((unsigned)wloc < 32u) {
                int pos = atomicAdd(&sh.sc.lcnt[wloc], 1);
                if (pos < CAP) sh.sc.lists[wloc][pos] = pr.x;
            }
        }
    }
    __syncthreads();

    // ---- Phase B: gather + mean ----
    const int sub = lane >> 3, f8 = lane & 7;
    const int r = wave * 8 + sub;
    const int row = blockIdx.x * 32 + r;
    float acc[8] = {0.f, 0.f, 0.f, 0.f, 0.f, 0.f, 0.f, 0.f};
    add8(acc, xh[(row + 1) * 8 + f8]);    // self loop

    const int ctrue = sh.sc.lcnt[r];
    const int c = (ctrue < CAP) ? ctrue : CAP;
    const int* sp = (const int*)&sh.sc.lists[r][0];
    for (int i = 0; i < c; i += 4) {
        int4 e = *(const int4*)(sp + i);   // LDS, 16B aligned (CAP%4==0)
        int e1 = (i + 1 < c) ? e.y : -1;
        int e2 = (i + 2 < c) ? e.z : -1;
        int e3 = (i + 3 < c) ? e.w : -1;
        uint4 v0 = xh[(e.x + 1) * 8 + f8];
        uint4 v1 = xh[(e1 + 1) * 8 + f8];
        uint4 v2 = xh[(e2 + 1) * 8 + f8];
        uint4 v3 = xh[(e3 + 1) * 8 + f8];
        add8(acc, v0);
        add8(acc, v1);
        add8(acc, v2);
        add8(acc, v3);
    }

    const float inv = 1.0f / (float)(ctrue + 1);
#pragma unroll
    for (int k = 0; k < 8; ++k) acc[k] *= inv;

    __syncthreads();      // all waves done reading sc before ab overwrites it

    // ---- stage aggr tile to LDS as bf16 (overlays scan storage) ----
    uint4 pk;
    pk.x = pack2(acc[0], acc[1]);
    pk.y = pack2(acc[2], acc[3]);
    pk.z = pack2(acc[4], acc[5]);
    pk.w = pack2(acc[6], acc[7]);
    *(uint4*)&sh.mm.ab[(wave * 8 + sub) * 72 + f8 * 8] = pk;
    __syncthreads();

    // ---- Phase C: MFMA lin[32][64] = aggr @ W^T ----
    const int mh = wave & 1, nh = wave >> 1;    // quadrant
    const int m = lane & 15, quad = lane >> 4;

    const unsigned short* ap = &sh.mm.ab[(mh * 16 + m) * 72 + quad * 8];
    short8_t a0 = *(const short8_t*)ap;          // k = 0..31
    short8_t a1 = *(const short8_t*)(ap + 32);   // k = 32..63

    const unsigned short* bp0 = Wb + (nh * 32 + m) * 64 + quad * 8;
    short8_t b00 = *(const short8_t*)bp0;
    short8_t b01 = *(const short8_t*)(bp0 + 32);
    const unsigned short* bp1 = bp0 + 16 * 64;
    short8_t b10 = *(const short8_t*)bp1;
    short8_t b11 = *(const short8_t*)(bp1 + 32);

    f32x4 c0 = {0.f, 0.f, 0.f, 0.f}, c1 = {0.f, 0.f, 0.f, 0.f};
    c0 = __builtin_amdgcn_mfma_f32_16x16x32_bf16(a0, b00, c0, 0, 0, 0);
    c0 = __builtin_amdgcn_mfma_f32_16x16x32_bf16(a1, b01, c0, 0, 0, 0);
    c1 = __builtin_amdgcn_mfma_f32_16x16x32_bf16(a0, b10, c1, 0, 0, 0);
    c1 = __builtin_amdgcn_mfma_f32_16x16x32_bf16(a1, b11, c1, 0, 0, 0);

    // ---- epilogue: bias, store, per-feature stats ----
    const int rb = blockIdx.x * 32 + mh * 16 + quad * 4;
#pragma unroll
    for (int f = 0; f < 2; ++f) {
        f32x4 cc = f ? c1 : c0;
        int col = nh * 32 + f * 16 + m;          // C/D: col=lane&15
        float bj = bias[col];
        float q0 = 0.f, q1 = 0.f;
#pragma unroll
        for (int rr = 0; rr < 4; ++rr) {         // C/D: row=quad*4+rr
            float v = cc[rr] + bj;
            lin_out[(rb + rr) * DIM + col] = v;
            q0 += v;
            q1 += v * v;
        }
        q0 += __shfl_xor(q0, 16); q0 += __shfl_xor(q0, 32);
        q1 += __shfl_xor(q1, 16); q1 += __shfl_xor(q1, 32);
        if (quad == 0) {
            sh.mm.red0[wave][f * 16 + m] = q0;
            sh.mm.red1[wave][f * 16 + m] = q1;
        }
    }
    __syncthreads();
    if (threadIdx.x < DIM) {
        int j = threadIdx.x, jh = j >> 5, jl = j & 31;
        float t0 = sh.mm.red0[2 * jh][jl] + sh.mm.red0[2 * jh + 1][jl];
        float t1 = sh.mm.red1[2 * jh][jl] + sh.mm.red1[2 * jh + 1][jl];
        float* sbk = stats8 + (blockIdx.x & 7) * 128;
        atomicAdd(&sbk[j], t0);
        atomicAdd(&sbk[DIM + j], t1);
    }
}

// ---------------------------------------------------------------------------
// Kernel 3: out = relu(lin*scale + shift + x_bf16), BN params from stats.
// ---------------------------------------------------------------------------
__global__ __launch_bounds__(256) void k_final(const float4* lin4,
                                               const unsigned short* __restrict__ xh16,
                                               const float* __restrict__ stats8,
                                               const float* __restrict__ gamma,
                                               const float* __restrict__ beta,
                                               float4* out4) {
    __shared__ float ss[2][DIM];
    if (threadIdx.x < DIM) {
        int j = threadIdx.x;
        float s0 = 0.f, s1 = 0.f;
#pragma unroll
        for (int b = 0; b < 8; ++b) {
            s0 += stats8[b * 128 + j];
            s1 += stats8[b * 128 + DIM + j];
        }
        const float invN = 1.0f / (float)N_NODES;
        float mean = s0 * invN;
        float var = s1 * invN - mean * mean;
        float scale = gamma[j] * rsqrtf(var + BN_EPS);
        ss[0][j] = scale;
        ss[1][j] = beta[j] - mean * scale;
    }
    __syncthreads();
    int tid = blockIdx.x * blockDim.x + threadIdx.x;
    int row = tid >> 4;
    int j4 = (tid & 15) * 4;
    float4 l = lin4[tid];
    ushort2 h01 = *(const ushort2*)&xh16[(row + 1) * 64 + j4];
    ushort2 h23 = *(const ushort2*)&xh16[(row + 1) * 64 + j4 + 2];
    float4 o;
    o.x = fmaxf(fmaf(l.x, ss[0][j4 + 0], ss[1][j4 + 0])
                + __uint_as_float((unsigned)h01.x << 16), 0.f);
    o.y = fmaxf(fmaf(l.y, ss[0][j4 + 1], ss[1][j4 + 1])
                + __uint_as_float((unsigned)h01.y << 16), 0.f);
    o.z = fmaxf(fmaf(l.z, ss[0][j4 + 2], ss[1][j4 + 2])
                + __uint_as_float((unsigned)h23.x << 16), 0.f);
    o.w = fmaxf(fmaf(l.w, ss[0][j4 + 3], ss[1][j4 + 3])
                + __uint_as_float((unsigned)h23.y << 16), 0.f);
    out4[tid] = o;
}

// ---------------------------------------------------------------------------
extern "C" void kernel_launch(void* const* d_in, const int* in_sizes, int n_in,
                              void* d_out, int out_size, void* d_ws, size_t ws_size,
                              hipStream_t stream) {
    const float* x     = (const float*)d_in[0];
    const int*   ei    = (const int*)d_in[1];
    const float* W     = (const float*)d_in[2];
    const float* bias  = (const float*)d_in[3];
    const float* gamma = (const float*)d_in[4];
    const float* beta  = (const float*)d_in[5];
    float* out = (float*)d_out;

    // ws layout (bytes):
    //   stats8  @ 0          4096
    //   seg_cnt @ 4096       512
    //   ovf_cnt @ 4608       128
    //   ovf     @ 4736       32768          -> control ends 37504
    //   xh      @ 37504      12800128       ((N+1) x 128 B; row 0 zeroed by
    //                                        the same memset: [0, 37632))
    //   Wb      @ 12837632   8192
    //   seg_buf @ 12845824   4415488        (NSEG * SEGCAP * 4) -> 17261312
    char* ws = (char*)d_ws;
    float*          stats8  = (float*)(ws);
    int*            seg_cnt = (int*)(ws + 4096);
    int*            ovf_cnt = (int*)(ws + 4608);
    uint2*          ovf     = (uint2*)(ws + 4736);
    uint4*          xh      = (uint4*)(ws + 37504);
    unsigned short* Wb      = (unsigned short*)(ws + 12837632);
    unsigned*       seg_buf = (unsigned*)(ws + 12845824);

    hipMemsetAsync(ws, 0, 37632, stream);   // control block + xh zero row

    k_bin1<<<NBIN1 + CONV_BLOCKS + 1, 256, 0, stream>>>(
        ei, (const float4*)x, W, seg_buf, seg_cnt, ovf_cnt, ovf, xh, Wb);

    k_gather_linear<<<GATHER_BLOCKS, 256, 0, stream>>>(
        xh, seg_buf, seg_cnt, ovf_cnt, ovf, Wb, bias, out, stats8);

    k_final<<<N_NODES * (DIM / 4) / 256, 256, 0, stream>>>(
        (const float4*)out, (const unsigned short*)xh, stats8, gamma, beta,
        (float4*)out);
}